// Round 5
// baseline (459.454 us; speedup 1.0000x reference)
//
#include <hip/hip_runtime.h>

#define N_NODES 100000
#define IN_CH 16
#define HIDDEN 32
#define NUM_HH 1000

#define NPB 128                                   // nodes per bucket
#define NBUCK ((N_NODES + NPB - 1) / NPB)         // 782
#define NCHUNK 512                                // edge chunks (pass A/B blocks)
#define SCAN_N (NBUCK * NCHUNK)                   // 400384
#define S1_BLOCKS ((SCAN_N + 1023) / 1024)        // 391
#define SORT_CAP 6144                             // bucket mean 4096, std ~64

// ---------------------------------------------------------------------------
// Pass A: per-chunk bucket histogram (LDS), write counts[bucket][chunk].
// ---------------------------------------------------------------------------
__global__ __launch_bounds__(256) void passA_count(const int* __restrict__ dst,
                                                   int* __restrict__ counts,
                                                   int n_edges, int cepb) {
  __shared__ int hist[NBUCK];
  for (int i = threadIdx.x; i < NBUCK; i += 256) hist[i] = 0;
  __syncthreads();
  const int s = blockIdx.x * cepb;
  const int e = min(n_edges, s + cepb);
  for (int i = s + threadIdx.x; i < e; i += 256)
    atomicAdd(&hist[dst[i] >> 7], 1);
  __syncthreads();
  for (int i = threadIdx.x; i < NBUCK; i += 256)
    counts[i * NCHUNK + blockIdx.x] = hist[i];
}

// ---------------------------------------------------------------------------
// Exclusive scan over SCAN_N ints (bucket-major order).
// ---------------------------------------------------------------------------
__global__ __launch_bounds__(1024) void scan_local(const int* __restrict__ in,
                                                   int* __restrict__ out,
                                                   int* __restrict__ partials) {
  __shared__ int tmp[1024];
  const int i = blockIdx.x * 1024 + threadIdx.x;
  const int v = (i < SCAN_N) ? in[i] : 0;
  tmp[threadIdx.x] = v;
  __syncthreads();
  for (int off = 1; off < 1024; off <<= 1) {
    int t = (threadIdx.x >= off) ? tmp[threadIdx.x - off] : 0;
    __syncthreads();
    tmp[threadIdx.x] += t;
    __syncthreads();
  }
  if (i < SCAN_N) out[i] = tmp[threadIdx.x] - v;  // exclusive
  if (threadIdx.x == 1023) partials[blockIdx.x] = tmp[threadIdx.x];
}

__global__ __launch_bounds__(512) void scan_partials(int* __restrict__ partials) {
  __shared__ int tmp[512];
  const int v = (threadIdx.x < S1_BLOCKS) ? partials[threadIdx.x] : 0;
  tmp[threadIdx.x] = v;
  __syncthreads();
  for (int off = 1; off < 512; off <<= 1) {
    int t = (threadIdx.x >= off) ? tmp[threadIdx.x - off] : 0;
    __syncthreads();
    tmp[threadIdx.x] += t;
    __syncthreads();
  }
  if (threadIdx.x < S1_BLOCKS) partials[threadIdx.x] = tmp[threadIdx.x] - v;
}

__global__ __launch_bounds__(1024) void scan_add(int* __restrict__ out,
                                                 const int* __restrict__ partials,
                                                 int* __restrict__ bucket_ptr,
                                                 int n_edges) {
  const int i = blockIdx.x * 1024 + threadIdx.x;
  if (i < SCAN_N) {
    const int v = out[i] + partials[blockIdx.x];
    out[i] = v;
    if ((i & (NCHUNK - 1)) == 0) bucket_ptr[i / NCHUNK] = v;
  }
  if (i == 0) bucket_ptr[NBUCK] = n_edges;
}

// ---------------------------------------------------------------------------
// Pass B: scatter packed (src | local<<17) into per-(bucket,chunk) regions.
// ---------------------------------------------------------------------------
__global__ __launch_bounds__(256) void passB_scatter(
    const int* __restrict__ src, const int* __restrict__ dst,
    const int* __restrict__ offs, unsigned* __restrict__ packed, int n_edges,
    int cepb) {
  __shared__ int cur[NBUCK];
  for (int i = threadIdx.x; i < NBUCK; i += 256)
    cur[i] = offs[i * NCHUNK + blockIdx.x];
  __syncthreads();
  const int s = blockIdx.x * cepb;
  const int e = min(n_edges, s + cepb);
  for (int i = s + threadIdx.x; i < e; i += 256) {
    const int d = dst[i];
    const int b = d >> 7;
    const int pos = atomicAdd(&cur[b], 1);
    packed[pos] = (unsigned)src[i] | ((unsigned)(d & (NPB - 1)) << 17);
  }
}

// ---------------------------------------------------------------------------
// Bucket sort: one block per bucket, LDS counting sort by local node,
// scatter back IN PLACE (value = src only). Emits node-level row_ptr.
// ---------------------------------------------------------------------------
__global__ __launch_bounds__(512) void bucket_sort(
    unsigned* __restrict__ packed, const int* __restrict__ bucket_ptr,
    int* __restrict__ row_ptr, int n_edges) {
  __shared__ unsigned stage[SORT_CAP];
  __shared__ int bins[NPB];
  __shared__ int scn[NPB];
  __shared__ int cur[NPB];
  const int b = blockIdx.x;
  const int s = bucket_ptr[b];
  const int cnt = bucket_ptr[b + 1] - s;
  const int tid = threadIdx.x;

  if (tid < NPB) bins[tid] = 0;
  __syncthreads();
  for (int i = tid; i < cnt; i += 512) {
    const unsigned pk = packed[s + i];
    stage[i] = pk;
    atomicAdd(&bins[pk >> 17], 1);
  }
  __syncthreads();
  if (tid < NPB) scn[tid] = bins[tid];
  __syncthreads();
  for (int off = 1; off < NPB; off <<= 1) {
    int t = (tid < NPB && tid >= off) ? scn[tid - off] : 0;
    __syncthreads();
    if (tid < NPB) scn[tid] += t;
    __syncthreads();
  }
  if (tid < NPB) {
    const int excl = scn[tid] - bins[tid];
    cur[tid] = excl;
    const int node = b * NPB + tid;
    if (node < N_NODES) row_ptr[node] = s + excl;
  }
  if (b == NBUCK - 1 && tid == 0) row_ptr[N_NODES] = n_edges;
  __syncthreads();
  for (int i = tid; i < cnt; i += 512) {
    const unsigned pk = stage[i];
    const int pos = atomicAdd(&cur[pk >> 17], 1);
    packed[s + pos] = pk & 0x1FFFFu;  // sorted; strip local bits
  }
}

// ---------------------------------------------------------------------------
// Fused SAGE layer, one block per 128-node bucket, 8 waves, 16 node-passes.
// Weights staged ONCE per block. Per pass each wave owns one node:
//   gather feat[adj[i]] quads -> shfl_xor butterfly -> per-wave LDS slot ->
//   in-wave GEMV: relu(mean@w_l + x@w_r + b).
// If FC: h rows stay in LDS; after all passes, FC head streams
//   out[n,0:1000] = hs[n]@fc_w + fc_b (broadcast LDS reads, coalesced stores).
// ---------------------------------------------------------------------------
template <int CH, bool FC>
__global__ __launch_bounds__(512) void sage_block(
    const float* __restrict__ feat, const int* __restrict__ row_ptr,
    const int* __restrict__ adj, const float* __restrict__ w_l,
    const float* __restrict__ w_r, const float* __restrict__ b,
    float* __restrict__ out, const float* __restrict__ fcw,
    const float* __restrict__ fcb) {
  constexpr int Q = CH / 4;    // lanes per edge row
  constexpr int EPW = 64 / Q;  // edges per wave iteration
  __shared__ float wl[CH * HIDDEN];
  __shared__ float wr[CH * HIDDEN];
  __shared__ float bs[HIDDEN];
  __shared__ float mean_s[8][CH];
  __shared__ float xs[8][CH];
  __shared__ float hs[FC ? NPB * HIDDEN : 1];

  const int tid = threadIdx.x;
  for (int i = tid; i < CH * HIDDEN; i += 512) {
    wl[i] = w_l[i];
    wr[i] = w_r[i];
  }
  if (tid < HIDDEN) bs[tid] = b[tid];
  __syncthreads();

  const int wave = tid >> 6;
  const int lane = tid & 63;
  const int base = blockIdx.x * NPB;
  const int q = lane & (Q - 1);
  const int esub = lane / Q;
  const int j = lane & 31;
  const int p = lane >> 5;

#pragma unroll 1
  for (int pass = 0; pass < NPB / 8; ++pass) {
    const int l = pass * 8 + wave;  // local node index in bucket
    const int n = base + l;
    if (n < N_NODES) {  // wave-uniform guard
      const int s = row_ptr[n];
      const int e = row_ptr[n + 1];

      float4 acc = {0.f, 0.f, 0.f, 0.f};
      for (int i = s + esub; i < e; i += EPW) {
        const float4 v = ((const float4*)(feat + (size_t)adj[i] * CH))[q];
        acc.x += v.x;
        acc.y += v.y;
        acc.z += v.z;
        acc.w += v.w;
      }
#pragma unroll
      for (int m = Q; m < 64; m <<= 1) {
        acc.x += __shfl_xor(acc.x, m, 64);
        acc.y += __shfl_xor(acc.y, m, 64);
        acc.z += __shfl_xor(acc.z, m, 64);
        acc.w += __shfl_xor(acc.w, m, 64);
      }
      const float inv = 1.0f / fmaxf((float)(e - s), 1.0f);
      if (esub == 0) {  // lane == q
        mean_s[wave][4 * q + 0] = acc.x * inv;
        mean_s[wave][4 * q + 1] = acc.y * inv;
        mean_s[wave][4 * q + 2] = acc.z * inv;
        mean_s[wave][4 * q + 3] = acc.w * inv;
        const float4 xv = ((const float4*)(feat + (size_t)n * CH))[q];
        xs[wave][4 * q + 0] = xv.x;
        xs[wave][4 * q + 1] = xv.y;
        xs[wave][4 * q + 2] = xv.z;
        xs[wave][4 * q + 3] = xv.w;
      }
      // intra-wave LDS RAW: in-order per-wave DS pipe; fence compiler only
      __builtin_amdgcn_wave_barrier();

      float o = 0.f;
#pragma unroll
      for (int k = p * (CH / 2); k < (p + 1) * (CH / 2); ++k)
        o = fmaf(mean_s[wave][k], wl[k * HIDDEN + j],
                 fmaf(xs[wave][k], wr[k * HIDDEN + j], o));
      o += __shfl_xor(o, 32, 64);
      o = fmaxf(o + bs[j], 0.f);
      if (p == 0) {
        if (FC)
          hs[l * HIDDEN + j] = o;
        else
          out[(size_t)n * HIDDEN + j] = o;
      }
      __builtin_amdgcn_wave_barrier();
    }
  }

  if (FC) {
    __syncthreads();
    const int nvalid = min(NPB, N_NODES - base);
#pragma unroll
    for (int c = 0; c < 2; ++c) {
      const int jj = c * 512 + tid;
      if (jj < NUM_HH) {
        float w[HIDDEN];
#pragma unroll
        for (int k = 0; k < HIDDEN; ++k) w[k] = fcw[k * NUM_HH + jj];
        const float bias = fcb[jj];
        for (int n = 0; n < nvalid; ++n) {
          float a = bias;
#pragma unroll
          for (int k = 0; k < HIDDEN; ++k)
            a = fmaf(hs[n * HIDDEN + k], w[k], a);
          out[(size_t)(base + n) * NUM_HH + jj] = a;
        }
      }
    }
  }
}

extern "C" void kernel_launch(void* const* d_in, const int* in_sizes, int n_in,
                              void* d_out, int out_size, void* d_ws,
                              size_t ws_size, hipStream_t stream) {
  const float* x = (const float*)d_in[0];
  const int* edge = (const int*)d_in[1];
  const float* w1_l = (const float*)d_in[2];
  const float* w1_r = (const float*)d_in[3];
  const float* b1 = (const float*)d_in[4];
  const float* w2_l = (const float*)d_in[5];
  const float* w2_r = (const float*)d_in[6];
  const float* b2 = (const float*)d_in[7];
  const float* fc_w = (const float*)d_in[8];
  const float* fc_b = (const float*)d_in[9];
  float* out = (float*)d_out;

  const int n_edges = in_sizes[1] / 2;
  const int* src = edge;
  const int* dst = edge + n_edges;

  // Workspace (~29 MB): packed/adj[E] | h1[N*32] | counts | offs | ptrs
  unsigned* packed = (unsigned*)d_ws;
  float* h1 = (float*)(packed + n_edges);
  int* counts = (int*)(h1 + (size_t)N_NODES * HIDDEN);
  int* offs = counts + SCAN_N;
  int* bucket_ptr = offs + SCAN_N;
  int* partials = bucket_ptr + NBUCK + 1;
  int* row_ptr = partials + S1_BLOCKS + 1;

  const int cepb = (n_edges + NCHUNK - 1) / NCHUNK;

  // ---- bucket partition + node-level counting sort (shared by both layers)
  passA_count<<<NCHUNK, 256, 0, stream>>>(dst, counts, n_edges, cepb);
  scan_local<<<S1_BLOCKS, 1024, 0, stream>>>(counts, offs, partials);
  scan_partials<<<1, 512, 0, stream>>>(partials);
  scan_add<<<S1_BLOCKS, 1024, 0, stream>>>(offs, partials, bucket_ptr, n_edges);
  passB_scatter<<<NCHUNK, 256, 0, stream>>>(src, dst, offs, packed, n_edges,
                                            cepb);
  bucket_sort<<<NBUCK, 512, 0, stream>>>(packed, bucket_ptr, row_ptr, n_edges);

  // ---- Layer 1 (CH=16): x -> h1 ----
  sage_block<IN_CH, false><<<NBUCK, 512, 0, stream>>>(
      x, row_ptr, (const int*)packed, w1_l, w1_r, b1, h1, nullptr, nullptr);
  // ---- Layer 2 (CH=32) + fused FC head: h1 -> out ----
  sage_block<HIDDEN, true><<<NBUCK, 512, 0, stream>>>(
      h1, row_ptr, (const int*)packed, w2_l, w2_r, b2, out, fc_w, fc_b);
}